// Round 6
// baseline (304.198 us; speedup 1.0000x reference)
//
#include <hip/hip_runtime.h>
#include <hip/hip_bf16.h>

#define D_FEAT 256
#define PBM 256     // rows per block (4 waves x 64)
#define CR  512     // cols per block range
#define CT  64      // cols per staged B tile
#define NT  (CR/CT) // 8 tiles per range

typedef float f32x4 __attribute__((ext_vector_type(4)));
typedef short bf16x8 __attribute__((ext_vector_type(8)));

// round-to-nearest-even f32 -> bf16 bits
__device__ __forceinline__ unsigned short f2bf(float f) {
  unsigned int u = __float_as_uint(f);
  u += 0x7fffu + ((u >> 16) & 1u);
  return (unsigned short)(u >> 16);
}

// raw v_exp_f32 (base-2)
__device__ __forceinline__ float exp2r(float x) {
  return __builtin_amdgcn_exp2f(x);
}

// Convert BOTH inputs to bf16, exact f32 row sq-norms, zero accumulators.
__global__ void prep_kernel(const float* __restrict__ X,
                            const float* __restrict__ Y,
                            unsigned short* __restrict__ Xb,
                            unsigned short* __restrict__ Yb,
                            float* __restrict__ xsq, float* __restrict__ ysq,
                            double* __restrict__ accum, int N, int M) {
  if (blockIdx.x == 0 && threadIdx.x < 3) accum[threadIdx.x] = 0.0;
  int row = blockIdx.x * 4 + (threadIdx.x >> 6);
  int lane = threadIdx.x & 63;
  if (row >= N + M) return;
  const float* src; unsigned short* dst; float* sq; int r;
  if (row < N) { src = X; dst = Xb; sq = xsq; r = row; }
  else         { src = Y; dst = Yb; sq = ysq; r = row - N; }
  float4 v = reinterpret_cast<const float4*>(src)[r * (D_FEAT / 4) + lane];
  float s = v.x * v.x + v.y * v.y + v.z * v.z + v.w * v.w;
  ushort4 o;
  o.x = f2bf(v.x); o.y = f2bf(v.y); o.z = f2bf(v.z); o.w = f2bf(v.w);
  reinterpret_cast<ushort4*>(dst)[r * (D_FEAT / 4) + lane] = o;
#pragma unroll
  for (int off = 32; off > 0; off >>= 1) s += __shfl_down(s, off);
  if (lane == 0) sq[r] = s;
}

// A-in-registers / B-streamed pair kernel.
// Block = 4 waves x 64 rows = 256-row panel, sweeping a 512-col range.
// Per wave: A (64 rows x K=256) lives in 128 VGPRs, loaded once.
// B streams through 2x32KB LDS tiles (64 cols x K=256), counted vmcnt.
// Epilogue (5-bw gaussian) fused per 32-col chunk inside the stream loop.
__global__ __launch_bounds__(256, 2)
void mmd_pair_kernel(const unsigned short* __restrict__ Xb,
                     const unsigned short* __restrict__ Yb,
                     const float* __restrict__ xsq,
                     const float* __restrict__ ysq,
                     double* __restrict__ accum,
                     int crx, int cry, int num_xy, int num_xx) {
  __shared__ unsigned short Bs[2][CT * D_FEAT];   // 2 x 32 KB
  __shared__ float wsum[4];

  // XCD-chunked bijective remap: consecutive logical blocks (same A-panel)
  // land on the same XCD -> A-panel + range reads hit that XCD's L2.
  int grid = gridDim.x;
  int q8 = grid >> 3, r8 = grid & 7;
  int xcd = blockIdx.x & 7, slot = blockIdx.x >> 3;
  int l = (xcd < r8) ? (xcd * (q8 + 1) + slot)
                     : (r8 * (q8 + 1) + (xcd - r8) * q8 + slot);

  const unsigned short *Ap, *Bp;
  const float *asq, *bsq;
  int ti, c0, accIdx;
  float wt;
  bool pred = false;

  if (l < num_xy) {
    ti = l / cry; c0 = (l - ti * cry) * CR;
    Ap = Xb; Bp = Yb; asq = xsq; bsq = ysq; accIdx = 2; wt = 1.0f;
  } else {
    int l2 = l - num_xy, cr_;
    if (l2 < num_xx) { Ap = Xb; Bp = Xb; asq = xsq; bsq = xsq; accIdx = 0; cr_ = crx; }
    else { l2 -= num_xx; Ap = Yb; Bp = Yb; asq = ysq; bsq = ysq; accIdx = 1; cr_ = cry; }
    // panel ti has (cr_ - ti/2) ranges, starting at col ((ti/2)*CR)
    ti = 0;
    for (;;) { int np = cr_ - (ti >> 1); if (l2 < np) break; l2 -= np; ++ti; }
    c0 = ((ti >> 1) + l2) * CR;
    pred = (l2 == 0);       // range containing the diagonal: strict col>row
    wt = 2.0f;
  }

  int tid = threadIdx.x, wid = tid >> 6, lane = tid & 63;
  int lrow = lane & 15, lk = lane >> 4;     // fragment row / k-quarter
  int swz = (lane & 7) << 4;                // LDS XOR swizzle (bits 4-6)

  // ---- A panel -> registers (64 rows x 256 K per wave, 32 loads of 16B)
  bf16x8 areg[4][8];
  {
    const char* Arow = (const char*)Ap +
        ((size_t)ti * PBM + wid * 64 + lrow) * (D_FEAT * 2) + lk * 16;
#pragma unroll
    for (int m = 0; m < 4; ++m)
#pragma unroll
      for (int k = 0; k < 8; ++k)
        areg[m][k] = *(const bf16x8*)(Arow + m * 16 * (D_FEAT * 2) + k * 64);
  }
  int rbase = ti * PBM + wid * 64 + lk * 4; // C-layout row base
  float xsr[4][4];
#pragma unroll
  for (int m = 0; m < 4; ++m)
#pragma unroll
    for (int j = 0; j < 4; ++j) xsr[m][j] = asq[rbase + m * 16 + j];

  // ---- B staging: tile t = 64 cols x 256 K = 32 KB; 8 loads/thread.
  // LDS row r (=output col) at r*512B; byte q holds global (r, q^((r&7)<<4)).
  auto stage = [&](int t, int b) {
    const char* Brow = (const char*)Bp;
    int gc0 = c0 + t * CT;
#pragma unroll
    for (int i = 0; i < 8; ++i) {
      int c = wid * 8 + i;                  // 1KB chunk = 2 rows
      int rr = c * 2 + (lane >> 5);
      size_t roff = (size_t)(gc0 + rr) * (D_FEAT * 2) +
                    (((lane & 31) * 16) ^ ((rr & 7) << 4));
      __builtin_amdgcn_global_load_lds(
          (const __attribute__((address_space(1))) unsigned int*)(Brow + roff),
          (__attribute__((address_space(3))) unsigned int*)((char*)Bs[b] + c * 1024),
          16, 0, 0);
    }
  };

  const float C0 = (float)(-18.033688010972094);   // bw 0.2 (x log2e)
  const float C1 = (float)(-2.8853900817555354);   // bw 0.5
  const float C2 = (float)(-0.7213475204388839);   // bw 1.0
  const float C3 = (float)(-0.18033688010972097);  // bw 2.0
  const float C4 = (float)(-0.028853900817555354); // bw 5.0

  float sum = 0.f;

  // per-tile compute: 2 chunks of 2 col-frags; 8 k-steps; fused epilogue
  auto compute = [&](int t, int b) {
    const char* Bt = (const char*)Bs[b];
    int gc0 = c0 + t * CT;
#pragma unroll
    for (int cn = 0; cn < 2; ++cn) {
      f32x4 acc2[4][2];
#pragma unroll
      for (int m = 0; m < 4; ++m)
#pragma unroll
        for (int nn = 0; nn < 2; ++nn) acc2[m][nn] = (f32x4){0.f, 0.f, 0.f, 0.f};
#pragma unroll
      for (int k = 0; k < 8; ++k) {
        int kb = (k * 64 + lk * 16) ^ swz;
        bf16x8 b0 = *(const bf16x8*)(Bt + (cn * 32 + lrow) * 512 + kb);
        bf16x8 b1 = *(const bf16x8*)(Bt + (cn * 32 + 16 + lrow) * 512 + kb);
#pragma unroll
        for (int m = 0; m < 4; ++m) {
          acc2[m][0] = __builtin_amdgcn_mfma_f32_16x16x32_bf16(areg[m][k], b0, acc2[m][0], 0, 0, 0);
          acc2[m][1] = __builtin_amdgcn_mfma_f32_16x16x32_bf16(areg[m][k], b1, acc2[m][1], 0, 0, 0);
        }
      }
      float ysc[2];
      ysc[0] = bsq[gc0 + cn * 32 + lrow];
      ysc[1] = bsq[gc0 + cn * 32 + 16 + lrow];
#pragma unroll
      for (int m = 0; m < 4; ++m)
#pragma unroll
        for (int nn = 0; nn < 2; ++nn) {
          float tv[4], es[4];
#pragma unroll
          for (int j = 0; j < 4; ++j)
            tv[j] = fmaf(-2.0f, acc2[m][nn][j], xsr[m][j] + ysc[nn]);
          float tmin = fminf(fminf(tv[0], tv[1]), fminf(tv[2], tv[3]));
#pragma unroll
          for (int j = 0; j < 4; ++j)
            es[j] = exp2r(tv[j] * C3) + exp2r(tv[j] * C4);
          if (__any(tmin < 210.0f)) {   // d2>210: C0..C2 underflow to 0 exactly
#pragma unroll
            for (int j = 0; j < 4; ++j) {
              float d2 = fmaxf(tv[j], 0.0f);
              es[j] += exp2r(d2 * C0) + exp2r(d2 * C1) + exp2r(d2 * C2);
            }
          }
          if (pred) {                   // strict upper triangle only
            int colg = gc0 + cn * 32 + nn * 16 + lrow;
#pragma unroll
            for (int j = 0; j < 4; ++j)
              if (colg <= rbase + m * 16 + j) es[j] = 0.0f;
          }
          sum += (es[0] + es[1]) + (es[2] + es[3]);
        }
    }
  };

  // ---- pipeline: dbuf, counted vmcnt (never 0 mid-loop)
  stage(0, 0);
  stage(1, 1);
  asm volatile("s_waitcnt vmcnt(8)" ::: "memory");  // A + tile0 landed
  __builtin_amdgcn_s_barrier();

#pragma unroll 2
  for (int t = 0; t < NT; ++t) {
    int b = t & 1;
    compute(t, b);
    __builtin_amdgcn_s_barrier();                   // all waves done with buf b
    asm volatile("" ::: "memory");
    if (t + 2 < NT) {
      stage(t + 2, b);
      asm volatile("s_waitcnt vmcnt(8)" ::: "memory");  // tile t+1 landed
      __builtin_amdgcn_s_barrier();
    } else if (t + 2 == NT) {
      asm volatile("s_waitcnt vmcnt(0)" ::: "memory");  // last tile landed
      __builtin_amdgcn_s_barrier();
    }
  }

#pragma unroll
  for (int off = 32; off > 0; off >>= 1) sum += __shfl_down(sum, off);
  if (lane == 0) wsum[wid] = sum;
  __syncthreads();
  if (tid == 0) {
    double tot = (double)((wsum[0] + wsum[1]) + (wsum[2] + wsum[3])) * (double)wt;
    atomicAdd(&accum[accIdx], tot);
  }
}

__global__ void finalize_kernel(const double* __restrict__ accum,
                                float* __restrict__ out, int N, int M) {
  double dN = (double)N, dM = (double)M;
  double v = accum[0] / (5.0 * dN * dN) + accum[1] / (5.0 * dM * dM)
           - 2.0 * accum[2] / (5.0 * dN * dM) + 1.0 / dN + 1.0 / dM;
  out[0] = (float)v;
}

extern "C" void kernel_launch(void* const* d_in, const int* in_sizes, int n_in,
                              void* d_out, int out_size, void* d_ws, size_t ws_size,
                              hipStream_t stream) {
  const float* s = (const float*)d_in[0];
  const float* t = (const float*)d_in[1];
  int N = in_sizes[0] / D_FEAT;
  int M = in_sizes[1] / D_FEAT;

  char* ws = (char*)d_ws;
  unsigned short* Xb = (unsigned short*)ws;
  unsigned short* Yb = Xb + (size_t)N * D_FEAT;
  float* xsq = (float*)(Yb + (size_t)M * D_FEAT);
  float* ysq = xsq + N;
  double* accum = (double*)(((uintptr_t)(ysq + M) + 15) & ~(uintptr_t)15);

  prep_kernel<<<(N + M + 3) / 4, 256, 0, stream>>>(s, t, Xb, Yb, xsq, ysq,
                                                   accum, N, M);

  int nrpx = N / PBM, nrpy = M / PBM;
  int crx = N / CR, cry = M / CR;
  int num_xy = nrpx * cry;
  int num_xx = 0, num_yy = 0;
  for (int p = 0; p < nrpx; ++p) num_xx += crx - (p >> 1);
  for (int p = 0; p < nrpy; ++p) num_yy += cry - (p >> 1);
  int grid = num_xy + num_xx + num_yy;

  mmd_pair_kernel<<<grid, 256, 0, stream>>>(Xb, Yb, xsq, ysq, accum,
                                            crx, cry, num_xy, num_xx);
  finalize_kernel<<<1, 1, 0, stream>>>(accum, (float*)d_out, N, M);
}

// Round 7
// 123.591 us; speedup vs baseline: 2.4613x; 2.4613x over previous
//
#include <hip/hip_runtime.h>

#define D_FEAT 256
#define BM 128      // block tile (M and N)

typedef int   i32x4  __attribute__((ext_vector_type(4)));
typedef int   i32x8  __attribute__((ext_vector_type(8)));
typedef float f32x16 __attribute__((ext_vector_type(16)));

__device__ __forceinline__ float exp2r(float x) { return __builtin_amdgcn_exp2f(x); }

// f32 -> OCP e4m3fn byte, round-to-nearest-even, saturate at 448.
__device__ __forceinline__ unsigned int f2e4m3(float f) {
  unsigned s = (__float_as_uint(f) >> 24) & 0x80u;
  float a = fminf(fabsf(f), 448.0f);
  int e = (int)((__float_as_uint(a) >> 23) & 0xff) - 127;
  int k = e - 3; k = (k < -9) ? -9 : k;              // ulp = 2^k, denorm floor 2^-9
  float ulp = __uint_as_float((unsigned)(k + 127) << 23);
  float q = rintf(a / ulp) * ulp;                    // exact ops, RNE
  unsigned uq = __float_as_uint(q);
  int eq = (int)((uq >> 23) & 0xff) - 127;
  unsigned enc;
  if (q == 0.0f) enc = 0u;
  else if (eq < -6) enc = (unsigned)(q * 512.0f);    // denorm: n * 2^-9, exact
  else enc = ((unsigned)(eq + 7) << 3) | ((uq >> 20) & 7u);
  return enc | s;
}

// Convert BOTH inputs to e4m3, exact f32 row sq-norms, zero accumulators.
__global__ void prep_kernel(const float* __restrict__ X,
                            const float* __restrict__ Y,
                            unsigned char* __restrict__ Xq,
                            unsigned char* __restrict__ Yq,
                            float* __restrict__ xsq, float* __restrict__ ysq,
                            double* __restrict__ accum, int N, int M) {
  if (blockIdx.x == 0 && threadIdx.x < 3) accum[threadIdx.x] = 0.0;
  int row = blockIdx.x * 4 + (threadIdx.x >> 6);
  int lane = threadIdx.x & 63;
  if (row >= N + M) return;
  const float* src; unsigned char* dst; float* sq; int r;
  if (row < N) { src = X; dst = Xq; sq = xsq; r = row; }
  else         { src = Y; dst = Yq; sq = ysq; r = row - N; }
  float4 v = reinterpret_cast<const float4*>(src)[r * (D_FEAT / 4) + lane];
  float s = v.x * v.x + v.y * v.y + v.z * v.z + v.w * v.w;
  unsigned pk = f2e4m3(v.x) | (f2e4m3(v.y) << 8) |
                (f2e4m3(v.z) << 16) | (f2e4m3(v.w) << 24);
  reinterpret_cast<unsigned*>(dst)[r * (D_FEAT / 4) + lane] = pk;
#pragma unroll
  for (int off = 32; off > 0; off >>= 1) s += __shfl_down(s, off);
  if (lane == 0) sq[r] = s;
}

// load one 32B K-frag (row, kbyte 32-aligned) from XOR-swizzled LDS tile
__device__ __forceinline__ i32x8 ldfrag(const unsigned char* base, int row, int kbyte) {
  int sw = (row & 7) << 4;
  i32x4 lo = *(const i32x4*)(base + row * 256 + (kbyte ^ sw));
  i32x4 hi = *(const i32x4*)(base + row * 256 + ((kbyte + 16) ^ sw));
  i32x8 r;
  r[0] = lo[0]; r[1] = lo[1]; r[2] = lo[2]; r[3] = lo[3];
  r[4] = hi[0]; r[5] = hi[1]; r[6] = hi[2]; r[7] = hi[3];
  return r;
}

// Fused pair-tile kernel, fp8-MX MFMA (scale=1.0), full-K single staging:
// one barrier per block, no K-loop staging. 64KB LDS -> 2 blocks/CU.
__global__ __launch_bounds__(256, 2)
void mmd_pair_kernel(const unsigned char* __restrict__ Xq,
                     const unsigned char* __restrict__ Yq,
                     const float* __restrict__ xsq,
                     const float* __restrict__ ysq,
                     double* __restrict__ accum,
                     int ntx, int nty, int num_xy, int num_tri_x) {
  __shared__ __align__(16) unsigned char As[BM * 256];   // 32 KB
  __shared__ __align__(16) unsigned char Bs[BM * 256];   // 32 KB
  __shared__ float wsum[4];

  // XCD-chunked bijective remap (m204)
  int grid = gridDim.x;
  int q8 = grid >> 3, r8 = grid & 7;
  int xcd = blockIdx.x & 7, slot = blockIdx.x >> 3;
  int l = (xcd < r8) ? (xcd * (q8 + 1) + slot)
                     : (r8 * (q8 + 1) + (xcd - r8) * q8 + slot);

  const unsigned char *Ap, *Bp;
  const float *asq, *bsq;
  int ti, tj, accIdx;
  float wt = 1.0f;
  bool maskDiag = false;

  if (l < num_xy) {
    ti = l / nty; tj = l - ti * nty;
    Ap = Xq; Bp = Yq; asq = xsq; bsq = ysq; accIdx = 2;
  } else {
    int t = l - num_xy, nt;
    if (t < num_tri_x) {
      nt = ntx; Ap = Xq; Bp = Xq; asq = xsq; bsq = xsq; accIdx = 0;
    } else {
      t -= num_tri_x;
      nt = nty; Ap = Yq; Bp = Yq; asq = ysq; bsq = ysq; accIdx = 1;
    }
    ti = 0;
    while (t >= nt - ti) { t -= nt - ti; ++ti; }  // upper-tri decode, ti<=tj
    tj = ti + t;
    if (ti == tj) maskDiag = true; else wt = 2.0f;
  }

  int tid = threadIdx.x;
  int wid = tid >> 6, lane = tid & 63;
  int wm = wid >> 1, wn = wid & 1;          // 2x2 waves; 64x64 per wave
  int lc = lane & 31, hk = lane >> 5;       // frag row/col + K-half

  // ---- stage full-K A and B tiles (32 KB each), source pre-swizzled
  {
    const unsigned char* Ab = Ap + (size_t)ti * BM * 256;
    const unsigned char* Bb = Bp + (size_t)tj * BM * 256;
    int gr = tid & 15;                      // granule within row
    int swr = ((gr * 16));                  // byte pos of granule
#pragma unroll
    for (int i = 0; i < 8; ++i) {
      int row = i * 16 + (tid >> 4);
      size_t roff = (size_t)row * 256 + (swr ^ ((row & 7) << 4));
      // dest: linear, wave-uniform base + lane*16
      __builtin_amdgcn_global_load_lds(
          (const __attribute__((address_space(1))) unsigned int*)(Ab + roff),
          (__attribute__((address_space(3))) unsigned int*)(As + i * 4096 + wid * 1024),
          16, 0, 0);
      __builtin_amdgcn_global_load_lds(
          (const __attribute__((address_space(1))) unsigned int*)(Bb + roff),
          (__attribute__((address_space(3))) unsigned int*)(Bs + i * 4096 + wid * 1024),
          16, 0, 0);
    }
  }
  __syncthreads();   // single drain+barrier for the whole block

  // ---- K-loop: 4 x K=64 MX-fp8 MFMA, no barriers
  f32x16 acc[2][2];
#pragma unroll
  for (int m = 0; m < 2; ++m)
#pragma unroll
    for (int n = 0; n < 2; ++n)
#pragma unroll
      for (int j = 0; j < 16; ++j) acc[m][n][j] = 0.0f;

#pragma unroll
  for (int kt = 0; kt < 4; ++kt) {
    int kbyte = kt * 64 + hk * 32;
    i32x8 a0 = ldfrag(As, wm * 64 + lc, kbyte);
    i32x8 a1 = ldfrag(As, wm * 64 + 32 + lc, kbyte);
    i32x8 b0 = ldfrag(Bs, wn * 64 + lc, kbyte);
    i32x8 b1 = ldfrag(Bs, wn * 64 + 32 + lc, kbyte);
    acc[0][0] = __builtin_amdgcn_mfma_scale_f32_32x32x64_f8f6f4(
        a0, b0, acc[0][0], 0, 0, 0, 0x7f7f7f7f, 0, 0x7f7f7f7f);
    acc[0][1] = __builtin_amdgcn_mfma_scale_f32_32x32x64_f8f6f4(
        a0, b1, acc[0][1], 0, 0, 0, 0x7f7f7f7f, 0, 0x7f7f7f7f);
    acc[1][0] = __builtin_amdgcn_mfma_scale_f32_32x32x64_f8f6f4(
        a1, b0, acc[1][0], 0, 0, 0, 0x7f7f7f7f, 0, 0x7f7f7f7f);
    acc[1][1] = __builtin_amdgcn_mfma_scale_f32_32x32x64_f8f6f4(
        a1, b1, acc[1][1], 0, 0, 0, 0x7f7f7f7f, 0, 0x7f7f7f7f);
  }

  // ---- epilogue: d2 = |x|^2 + |y|^2 - 2*dot; 5-bandwidth gaussian sum.
  // C/D layout (32x32): col = lane&31, row = (reg&3) + 8*(reg>>2) + 4*(lane>>5)
  const float C0 = (float)(-18.033688010972094);   // bw 0.2  (x log2e)
  const float C1 = (float)(-2.8853900817555354);   // bw 0.5
  const float C2 = (float)(-0.7213475204388839);   // bw 1.0
  const float C3 = (float)(-0.18033688010972097);  // bw 2.0
  const float C4 = (float)(-0.028853900817555354); // bw 5.0
  // d2 > 210: C0..C2 args < -151 -> exactly 0 in f32. Off-diag d2 ~ 512+-50.

  int rbase = ti * BM + wm * 64 + 4 * hk;
  int cbase = tj * BM + wn * 64 + lc;
  float4 xsrv[2][4];
#pragma unroll
  for (int m = 0; m < 2; ++m)
#pragma unroll
    for (int q = 0; q < 4; ++q)
      xsrv[m][q] = *reinterpret_cast<const float4*>(&asq[rbase + m * 32 + q * 8]);
  float ysc[2];
  ysc[0] = bsq[cbase];
  ysc[1] = bsq[cbase + 32];

  float sum = 0.f;
#pragma unroll
  for (int m = 0; m < 2; ++m)
#pragma unroll
    for (int n = 0; n < 2; ++n) {
      float tv[16];
#pragma unroll
      for (int j = 0; j < 16; ++j) {
        float xs = ((const float*)&xsrv[m][j >> 2])[j & 3];
        tv[j] = fmaf(-2.0f, acc[m][n][j], xs + ysc[n]);
      }
      float tmin = tv[0];
#pragma unroll
      for (int j = 1; j < 16; ++j) tmin = fminf(tmin, tv[j]);
      float es[16];
#pragma unroll
      for (int j = 0; j < 16; ++j)
        es[j] = exp2r(tv[j] * C3) + exp2r(tv[j] * C4);
      if (__any(tmin < 210.0f)) {
#pragma unroll
        for (int j = 0; j < 16; ++j) {
          float d2 = fmaxf(tv[j], 0.0f);
          es[j] += exp2r(d2 * C0) + exp2r(d2 * C1) + exp2r(d2 * C2);
        }
      }
      if (maskDiag) {
        int colg = cbase + n * 32;
#pragma unroll
        for (int j = 0; j < 16; ++j) {
          int rowg = rbase + m * 32 + (j & 3) + 8 * (j >> 2);
          if (rowg == colg) es[j] = 0.0f;
        }
      }
      float s4 = 0.f;
#pragma unroll
      for (int j = 0; j < 16; ++j) s4 += es[j];
      sum += s4;
    }

#pragma unroll
  for (int off = 32; off > 0; off >>= 1) sum += __shfl_down(sum, off);
  if (lane == 0) wsum[wid] = sum;
  __syncthreads();
  if (tid == 0) {
    double t = (double)((wsum[0] + wsum[1]) + (wsum[2] + wsum[3])) * (double)wt;
    atomicAdd(&accum[accIdx], t);
  }
}

__global__ void finalize_kernel(const double* __restrict__ accum,
                                float* __restrict__ out, int N, int M) {
  double dN = (double)N, dM = (double)M;
  double v = accum[0] / (5.0 * dN * dN) + accum[1] / (5.0 * dM * dM)
           - 2.0 * accum[2] / (5.0 * dN * dM) + 1.0 / dN + 1.0 / dM;
  out[0] = (float)v;
}

extern "C" void kernel_launch(void* const* d_in, const int* in_sizes, int n_in,
                              void* d_out, int out_size, void* d_ws, size_t ws_size,
                              hipStream_t stream) {
  const float* s = (const float*)d_in[0];
  const float* t = (const float*)d_in[1];
  int N = in_sizes[0] / D_FEAT;
  int M = in_sizes[1] / D_FEAT;

  char* ws = (char*)d_ws;
  unsigned char* Xq = (unsigned char*)ws;
  unsigned char* Yq = Xq + (size_t)N * D_FEAT;
  float* xsq = (float*)(Yq + (size_t)M * D_FEAT);
  float* ysq = xsq + N;
  double* accum = (double*)(((uintptr_t)(ysq + M) + 15) & ~(uintptr_t)15);

  prep_kernel<<<(N + M + 3) / 4, 256, 0, stream>>>(s, t, Xq, Yq, xsq, ysq,
                                                   accum, N, M);

  int ntx = N / BM, nty = M / BM;
  int num_xy = ntx * nty;
  int num_tri_x = ntx * (ntx + 1) / 2;
  int num_tri_y = nty * (nty + 1) / 2;
  int grid = num_xy + num_tri_x + num_tri_y;
  mmd_pair_kernel<<<grid, 256, 0, stream>>>(Xq, Yq, xsq, ysq, accum,
                                            ntx, nty, num_xy, num_tri_x);
  finalize_kernel<<<1, 1, 0, stream>>>(accum, (float*)d_out, N, M);
}